// Round 18
// baseline (48.974 us; speedup 1.0000x reference)
//
#include <hip/hip_runtime.h>
#include <hip/hip_bf16.h>

// Self-attention: b=32, s=2048, d=32, f32 in/out.
// qkv: FUSED single launch, 1024 blocks x 256 thr, 64 rows/block, 4 thr/row.
//   x read once (8MB). Q/K stores tid-coalesced; K/V repacked via the
//   verified scatter->barrier->copy skeleton into the SAME KF/VP layouts
//   the frozen attn consumes (mappings cross-checked against R16).
// attn: BYTE-IDENTICAL to round-16 pass (frozen; 7 structural edits failed).
// ws: KF 4MB | VP 4MB | Qb 4MB.

typedef __attribute__((ext_vector_type(8))) short bf16x8;
typedef __attribute__((ext_vector_type(4))) short bf16x4;
typedef __attribute__((ext_vector_type(4))) float f32x4;
typedef __attribute__((ext_vector_type(2))) unsigned int u32x2;
typedef __attribute__((ext_vector_type(4))) unsigned int u32x4;

#if __has_builtin(__builtin_amdgcn_mfma_f32_16x16x16bf16_1k)
#define MFMA_PV(a, b, c) __builtin_amdgcn_mfma_f32_16x16x16bf16_1k(a, b, c, 0, 0, 0)
#elif defined(__HIP_DEVICE_COMPILE__)
#error "no 16x16x16 bf16 mfma builtin on device"
#else
#define MFMA_PV(a, b, c) (c) /* host stub, never executed */
#endif

__device__ __forceinline__ unsigned cvt_pk_bf16(float lo, float hi) {
  unsigned r;
  asm("v_cvt_pk_bf16_f32 %0, %1, %2" : "=v"(r) : "v"(lo), "v"(hi));
  return r;
}
__device__ __forceinline__ bf16x4 as_bf16x4(u32x2 u) {
  union { u32x2 a; bf16x4 b; } c; c.a = u; return c.b;
}

// ---------------- QKV projection (fused, 4 threads/row, x read once) ----------------
// grid 1024 blocks; block B handles rows [B*64, B*64+64) = KV chunk B.
__global__ __launch_bounds__(256) void qkv_kernel(
    const float* __restrict__ x, const float* __restrict__ w,
    unsigned short* __restrict__ Qb, unsigned short* __restrict__ KF,
    unsigned short* __restrict__ VP) {
  __shared__ float Wlds[3072];                     // 3 heads x 32 x 32 f32
  __shared__ float xs[2304];                       // 64 rows x 36 (pad +4)
  __shared__ __align__(16) unsigned char RP[4096]; // repack buffer (K, then V)
  int tid = threadIdx.x;
  int B = blockIdx.x;

  // stage x tile coalesced: 8KB = 256 thr x 2 f32x4
  const float* xg = x + (size_t)B * 2048;
#pragma unroll
  for (int k2 = 0; k2 < 2; ++k2) {
    int fi = k2 * 1024 + tid * 4;
    f32x4 v = *(const f32x4*)(xg + fi);
    *(f32x4*)(&xs[(fi >> 5) * 36 + (fi & 31)]) = v;
  }
#pragma unroll
  for (int i = 0; i < 12; ++i) Wlds[i * 256 + tid] = w[i * 256 + tid];
  __syncthreads();

  int L64 = tid >> 2, q = tid & 3;        // row-in-chunk, col quarter (outs q*8..q*8+8)
  int kt = L64 >> 4, n = L64 & 15;        // K fragment indices: L64 = kt*16 + n
  int g4 = (L64 >> 2) & 3, i4 = L64 & 3;  // V fragment indices: L64 = kt*16 + g4*4 + i4

  const float* xr = &xs[L64 * 36];
  f32x4 xv[8];
#pragma unroll
  for (int j = 0; j < 8; ++j) xv[j] = *(const f32x4*)(xr + j * 4);

  f32x4 aq0 = (f32x4)0.0f, aq1 = (f32x4)0.0f;
  f32x4 ak0 = (f32x4)0.0f, ak1 = (f32x4)0.0f;
  f32x4 av0 = (f32x4)0.0f, av1 = (f32x4)0.0f;
#pragma unroll
  for (int d = 0; d < 32; ++d) {
    float xd = xv[d >> 2][d & 3];
    const f32x4* w0 = (const f32x4*)&Wlds[d * 32 + q * 8];
    const f32x4* w1 = (const f32x4*)&Wlds[1024 + d * 32 + q * 8];
    const f32x4* w2 = (const f32x4*)&Wlds[2048 + d * 32 + q * 8];
    aq0 += xd * w0[0]; aq1 += xd * w0[1];
    ak0 += xd * w1[0]; ak1 += xd * w1[1];
    av0 += xd * w2[0]; av1 += xd * w2[1];
  }

  const float alpha = 1.4426950408889634f * 0.17677669529663687f; // log2e/sqrt(32)

  // ---- Q: direct, pre-scaled; byte addr = B*4096 + tid*16 (perfectly coalesced)
  {
    u32x4 oq;
    oq[0] = cvt_pk_bf16(aq0[0] * alpha, aq0[1] * alpha);
    oq[1] = cvt_pk_bf16(aq0[2] * alpha, aq0[3] * alpha);
    oq[2] = cvt_pk_bf16(aq1[0] * alpha, aq1[1] * alpha);
    oq[3] = cvt_pk_bf16(aq1[2] * alpha, aq1[3] * alpha);
    *(u32x4*)(Qb + (size_t)(B * 64 + L64) * 32 + q * 8) = oq;
  }

  // ---- K: fragment-order repack (chunk byte = kt*1024 + g*256 + n*16, g = q)
  {
    u32x4 ok;
    ok[0] = cvt_pk_bf16(ak0[0], ak0[1]);
    ok[1] = cvt_pk_bf16(ak0[2], ak0[3]);
    ok[2] = cvt_pk_bf16(ak1[0], ak1[1]);
    ok[3] = cvt_pk_bf16(ak1[2], ak1[3]);
    *(u32x4*)(RP + kt * 1024 + q * 256 + n * 16) = ok;
  }
  __syncthreads();
  *(u32x4*)((char*)KF + (size_t)B * 4096 + tid * 16) = *(const u32x4*)(RP + tid * 16);
  __syncthreads(); // RP reused for V below

  // ---- V: paired fragment-order repack (same mapping as R16, re-indexed):
  // short idx = (e>>4)*1024 + (kt>>1)*512 + g4*128 + (e&15)*8 + (kt&1)*4 + i4
  {
    unsigned short* Vl = (unsigned short*)RP;
    int sbase = (q >> 1) * 1024 + (kt >> 1) * 512 + g4 * 128 + (kt & 1) * 4 + i4;
#pragma unroll
    for (int oo = 0; oo < 8; ++oo) {
      float vv = (oo < 4) ? av0[oo] : av1[oo - 4];
      unsigned r = cvt_pk_bf16(vv, vv);
      int e = q * 8 + oo;
      Vl[sbase + (e & 15) * 8] = (unsigned short)(r & 0xffffu);
    }
  }
  __syncthreads();
  *(u32x4*)((char*)VP + (size_t)B * 4096 + tid * 16) = *(const u32x4*)(RP + tid * 16);
}

// ---------------- Flash attention (BYTE-IDENTICAL to round-16 pass) ----------------
#define SMAX(SF, I2) {                                           \
    float p0 = __builtin_amdgcn_exp2f(SF[0]);                    \
    float p1 = __builtin_amdgcn_exp2f(SF[1]);                    \
    float p2 = __builtin_amdgcn_exp2f(SF[2]);                    \
    float p3 = __builtin_amdgcn_exp2f(SF[3]);                    \
    lsum += (p0 + p1) + (p2 + p3);                               \
    pk[I2] = cvt_pk_bf16(p0, p1);                                \
    pk[I2 + 1] = cvt_pk_bf16(p2, p3); }

#define PVKT(KT, V0, V1, ACC0, ACC1) {                           \
    u32x2 bw; bw[0] = pk[2 * KT]; bw[1] = pk[2 * KT + 1];        \
    bf16x4 bb = as_bf16x4(bw);                                   \
    ACC0 = MFMA_PV(as_bf16x4(V0), bb, ACC0);                     \
    ACC1 = MFMA_PV(as_bf16x4(V1), bb, ACC1); }

// grid: 1024 blocks (32 b x 32 q-tiles of 64), 256 threads (4 waves x 16 q-rows)
__global__ __launch_bounds__(256, 4) void attn_kernel(
    const unsigned short* __restrict__ Qb, const unsigned short* __restrict__ KF,
    const unsigned short* __restrict__ VP, float* __restrict__ out) {
  __shared__ __align__(16) unsigned char lds[2][8192]; // 2 x (K 4KB | V 4KB)
  unsigned char* ldsb = &lds[0][0];
  int tid = threadIdx.x;
  int wv = tid >> 6, lane = tid & 63;
  int n = lane & 15, g = lane >> 4;

  // XCD-aware bijective swizzle (1024 % 8 == 0)
  int bid = blockIdx.x;
  int swz = (bid & 7) * 128 + (bid >> 3);
  int bi = swz >> 5, qt = swz & 31;

  size_t Rq = (size_t)bi * 2048 + qt * 64 + wv * 16;

  const unsigned char* Kg = (const unsigned char*)KF + (size_t)bi * 131072;
  const unsigned char* Vg = (const unsigned char*)VP + (size_t)bi * 131072;

  // staging: wave wv covers 2KB of the 8KB (K|V) tile; 2 x 16B per lane
  const unsigned char* sgp = (wv < 2 ? Kg : Vg) + (wv & 1) * 2048 + lane * 16;
  unsigned char* ldsw = ldsb + (wv < 2 ? 0 : 4096) + (wv & 1) * 2048 + lane * 16;

  bf16x8 qf = *(const bf16x8*)(Qb + (Rq + n) * 32 + g * 8);

  f32x4 oA0 = (f32x4)0.0f, oA1 = (f32x4)0.0f; // kt 0,1 x eblk 0,1
  f32x4 oB0 = (f32x4)0.0f, oB1 = (f32x4)0.0f; // kt 2,3 x eblk 0,1
  float lsum = 0.0f;

  bf16x8 kr0, kr1;

  // prologue: stage tile 0 into buf0
  kr0 = *(const bf16x8*)(sgp);
  kr1 = *(const bf16x8*)(sgp + 1024);
  sgp += 4096;
  *(bf16x8*)(ldsw) = kr0;
  *(bf16x8*)(ldsw + 1024) = kr1;
  __syncthreads();

  for (int t = 0; t < 32; ++t) {
    int buf = t & 1;
    if (t < 31) { // issue next tile's loads early (one compute phase of cover)
      kr0 = *(const bf16x8*)(sgp);
      kr1 = *(const bf16x8*)(sgp + 1024);
      sgp += 4096;
    }
    const unsigned char* Lp = ldsb + buf * 8192;
    bf16x8 kf0 = *(const bf16x8*)(Lp + lane * 16);
    bf16x8 kf1 = *(const bf16x8*)(Lp + lane * 16 + 1024);
    bf16x8 kf2 = *(const bf16x8*)(Lp + lane * 16 + 2048);
    bf16x8 kf3 = *(const bf16x8*)(Lp + lane * 16 + 3072);
    // V: 4 x b128, each = (kt=2p | kt=2p+1) pair for eblk e
    u32x4 w00 = *(const u32x4*)(Lp + 4096 + lane * 16);          // e0, kt0|kt1
    u32x4 w01 = *(const u32x4*)(Lp + 4096 + lane * 16 + 1024);   // e0, kt2|kt3
    u32x4 w10 = *(const u32x4*)(Lp + 4096 + lane * 16 + 2048);   // e1, kt0|kt1
    u32x4 w11 = *(const u32x4*)(Lp + 4096 + lane * 16 + 3072);   // e1, kt2|kt3
    u32x2 vf0; vf0[0] = w00[0]; vf0[1] = w00[1];
    u32x2 vf1; vf1[0] = w00[2]; vf1[1] = w00[3];
    u32x2 vf2; vf2[0] = w01[0]; vf2[1] = w01[1];
    u32x2 vf3; vf3[0] = w01[2]; vf3[1] = w01[3];
    u32x2 vf4; vf4[0] = w10[0]; vf4[1] = w10[1];
    u32x2 vf5; vf5[0] = w10[2]; vf5[1] = w10[3];
    u32x2 vf6; vf6[0] = w11[0]; vf6[1] = w11[1];
    u32x2 vf7; vf7[0] = w11[2]; vf7[1] = w11[3];
    f32x4 s0 = __builtin_amdgcn_mfma_f32_16x16x32_bf16(kf0, qf, (f32x4)0.0f, 0, 0, 0);
    f32x4 s1 = __builtin_amdgcn_mfma_f32_16x16x32_bf16(kf1, qf, (f32x4)0.0f, 0, 0, 0);
    f32x4 s2 = __builtin_amdgcn_mfma_f32_16x16x32_bf16(kf2, qf, (f32x4)0.0f, 0, 0, 0);
    f32x4 s3 = __builtin_amdgcn_mfma_f32_16x16x32_bf16(kf3, qf, (f32x4)0.0f, 0, 0, 0);
    unsigned pk[8];
    SMAX(s0, 0) SMAX(s1, 2) SMAX(s2, 4) SMAX(s3, 6)
    PVKT(0, vf0, vf4, oA0, oA1) PVKT(1, vf1, vf5, oA0, oA1)
    PVKT(2, vf2, vf6, oB0, oB1) PVKT(3, vf3, vf7, oB0, oB1)
    __syncthreads();              // all waves done reading buf
    if (t < 31) {
      unsigned char* Wp = ldsw + (buf ^ 1) * 8192;
      *(bf16x8*)(Wp) = kr0;       // compiler inserts vmcnt wait before ds_write
      *(bf16x8*)(Wp + 1024) = kr1;
      __syncthreads();            // stage of tile t+1 visible to all
    }
  }

  // full row-sum for q-row n: partials live in lanes n, n+16, n+32, n+48
  lsum += __shfl_xor(lsum, 16);
  lsum += __shfl_xor(lsum, 32);
  float inv = 1.0f / lsum;

  // O: lane(n,g) reg r holds O[q=Rq+n][e = eblk*16 + g*4 + r]
  f32x4 r0 = (oA0 + oB0) * inv;
  f32x4 r1 = (oA1 + oB1) * inv;
  float* ob = out + (Rq + n) * 32 + g * 4;
  *(f32x4*)(ob)      = r0;
  *(f32x4*)(ob + 16) = r1;
}

extern "C" void kernel_launch(void* const* d_in, const int* in_sizes, int n_in,
                              void* d_out, int out_size, void* d_ws, size_t ws_size,
                              hipStream_t stream) {
  const float* x = (const float*)d_in[0];
  const float* w = (const float*)d_in[1];
  float* out = (float*)d_out;

  unsigned short* KF = (unsigned short*)d_ws;          // 4MB, fragment-order K
  unsigned short* VP = KF + (size_t)65536 * 32;        // 4MB, paired fragment-order V
  unsigned short* Qb = VP + (size_t)65536 * 32;        // 4MB

  qkv_kernel<<<1024, 256, 0, stream>>>(x, w, Qb, KF, VP);
  attn_kernel<<<1024, 256, 0, stream>>>(Qb, KF, VP, out);
}

// Round 19
// 43.696 us; speedup vs baseline: 1.1208x; 1.1208x over previous
//
#include <hip/hip_runtime.h>
#include <hip/hip_bf16.h>

// Self-attention: b=32, s=2048, d=32, f32 in/out.
// qkv: MFMA projection (one 16x16x32 bf16 MFMA per 16 rows x 16 outs; 6/wave).
//   x and W cast to bf16 (error budget verified); alpha folded into W0 frags.
//   Outputs scattered to the SAME verified KF/VP/Qb layouts via the verified
//   scatter -> barrier -> coalesced-copy skeleton. 1024 blocks, 64 rows/block.
// attn: BYTE-IDENTICAL to rounds 16/18 pass (frozen).
// ws: KF 4MB | VP 4MB | Qb 4MB.

typedef __attribute__((ext_vector_type(8))) short bf16x8;
typedef __attribute__((ext_vector_type(4))) short bf16x4;
typedef __attribute__((ext_vector_type(4))) float f32x4;
typedef __attribute__((ext_vector_type(2))) unsigned int u32x2;
typedef __attribute__((ext_vector_type(4))) unsigned int u32x4;

#if __has_builtin(__builtin_amdgcn_mfma_f32_16x16x16bf16_1k)
#define MFMA_PV(a, b, c) __builtin_amdgcn_mfma_f32_16x16x16bf16_1k(a, b, c, 0, 0, 0)
#elif defined(__HIP_DEVICE_COMPILE__)
#error "no 16x16x16 bf16 mfma builtin on device"
#else
#define MFMA_PV(a, b, c) (c) /* host stub, never executed */
#endif

__device__ __forceinline__ unsigned cvt_pk_bf16(float lo, float hi) {
  unsigned r;
  asm("v_cvt_pk_bf16_f32 %0, %1, %2" : "=v"(r) : "v"(lo), "v"(hi));
  return r;
}
__device__ __forceinline__ bf16x4 as_bf16x4(u32x2 u) {
  union { u32x2 a; bf16x4 b; } c; c.a = u; return c.b;
}
__device__ __forceinline__ bf16x8 as_bf16x8(u32x4 u) {
  union { u32x4 a; bf16x8 b; } c; c.a = u; return c.b;
}

// ---------------- QKV projection (MFMA) ----------------
// grid 1024 blocks x 256 thr (4 waves); block B owns rows [B*64, B*64+64);
// wave wv owns rows B*64 + wv*16 .. +16. Lane(n,g): row = rows0+n.
__global__ __launch_bounds__(256) void qkv_kernel(
    const float* __restrict__ x, const float* __restrict__ w,
    unsigned short* __restrict__ Qb, unsigned short* __restrict__ KF,
    unsigned short* __restrict__ VP) {
  __shared__ float Wlds[3072];                      // 3 heads x 32 x 32 f32
  __shared__ __align__(16) unsigned char RP[12288]; // Q 4K | K 4K | V 4K
  int tid = threadIdx.x;
  int B = blockIdx.x;
  int wv = tid >> 6, lane = tid & 63;
  int n = lane & 15, g = lane >> 4;

#pragma unroll
  for (int i = 0; i < 12; ++i) Wlds[i * 256 + tid] = w[i * 256 + tid];
  __syncthreads();

  const float alpha = 1.4426950408889634f * 0.17677669529663687f; // log2e/sqrt(32)

  // W fragments (A operand): af[h][jh]: a[i] = W[h][g*8+i][jh*16+n] (*alpha for h=0)
  bf16x8 af[3][2];
#pragma unroll
  for (int h = 0; h < 3; ++h) {
#pragma unroll
    for (int jh = 0; jh < 2; ++jh) {
      float sc = (h == 0) ? alpha : 1.0f;
      u32x4 u;
#pragma unroll
      for (int p = 0; p < 4; ++p) {
        float lo = Wlds[h * 1024 + (g * 8 + 2 * p) * 32 + jh * 16 + n] * sc;
        float hi = Wlds[h * 1024 + (g * 8 + 2 * p + 1) * 32 + jh * 16 + n] * sc;
        u[p] = cvt_pk_bf16(lo, hi);
      }
      af[h][jh] = as_bf16x8(u);
    }
  }

  // x fragment (B operand): b[i] = x[row][g*8+i] in bf16
  int row = B * 64 + wv * 16 + n;
  const float* xp = x + (size_t)row * 32 + g * 8;
  f32x4 x0 = *(const f32x4*)(xp);
  f32x4 x1 = *(const f32x4*)(xp + 4);
  u32x4 ux;
  ux[0] = cvt_pk_bf16(x0[0], x0[1]);
  ux[1] = cvt_pk_bf16(x0[2], x0[3]);
  ux[2] = cvt_pk_bf16(x1[0], x1[1]);
  ux[3] = cvt_pk_bf16(x1[2], x1[3]);
  bf16x8 xf = as_bf16x8(ux);

  // D: lane(n,g) reg t = OUT[row = rows0+n][j = jh*16 + g*4 + t]
  // ---- Q: row-major region RP[0..4096): byte = wv*1024 + n*64 + j*2
#pragma unroll
  for (int jh = 0; jh < 2; ++jh) {
    f32x4 d = __builtin_amdgcn_mfma_f32_16x16x32_bf16(af[0][jh], xf, (f32x4)0.0f, 0, 0, 0);
    u32x2 o;
    o[0] = cvt_pk_bf16(d[0], d[1]);
    o[1] = cvt_pk_bf16(d[2], d[3]);
    *(u32x2*)(RP + wv * 1024 + n * 64 + (jh * 16 + g * 4) * 2) = o;
  }
  // ---- K: KF chunk layout (R18-verified): byte = kt*1024 + g2*256 + n*16 + half*8
  //      kt = wv; g2 = (jh*16+g*4)/8 = jh*2 + (g>>1); half = g&1
#pragma unroll
  for (int jh = 0; jh < 2; ++jh) {
    f32x4 d = __builtin_amdgcn_mfma_f32_16x16x32_bf16(af[1][jh], xf, (f32x4)0.0f, 0, 0, 0);
    u32x2 o;
    o[0] = cvt_pk_bf16(d[0], d[1]);
    o[1] = cvt_pk_bf16(d[2], d[3]);
    *(u32x2*)(RP + 4096 + wv * 1024 + (jh * 2 + (g >> 1)) * 256 + n * 16 + (g & 1) * 8) = o;
  }
  // ---- V: VP paired layout (R18-verified): short idx =
  //      (e>>4)*1024 + (kt>>1)*512 + g4*128 + (e&15)*8 + (kt&1)*4 + i4
  //      kt = wv; g4 = n>>2; i4 = n&3; e = jh*16 + g*4 + t
  {
    unsigned short* Vl = (unsigned short*)(RP + 8192);
    int sb = (wv >> 1) * 512 + (n >> 2) * 128 + (wv & 1) * 4 + (n & 3);
#pragma unroll
    for (int jh = 0; jh < 2; ++jh) {
      f32x4 d = __builtin_amdgcn_mfma_f32_16x16x32_bf16(af[2][jh], xf, (f32x4)0.0f, 0, 0, 0);
#pragma unroll
      for (int t = 0; t < 4; ++t) {
        int e = jh * 16 + g * 4 + t;
        unsigned r = cvt_pk_bf16(d[t], d[t]);
        Vl[sb + (e >> 4) * 1024 + (e & 15) * 8] = (unsigned short)(r & 0xffffu);
      }
    }
  }
  __syncthreads();

  // coalesced copy-out: 3 x 4KB chunks
  *(u32x4*)((char*)Qb + (size_t)B * 4096 + tid * 16) = *(const u32x4*)(RP + tid * 16);
  *(u32x4*)((char*)KF + (size_t)B * 4096 + tid * 16) = *(const u32x4*)(RP + 4096 + tid * 16);
  *(u32x4*)((char*)VP + (size_t)B * 4096 + tid * 16) = *(const u32x4*)(RP + 8192 + tid * 16);
}

// ---------------- Flash attention (BYTE-IDENTICAL to rounds 16/18 pass) ----------------
#define SMAX(SF, I2) {                                           \
    float p0 = __builtin_amdgcn_exp2f(SF[0]);                    \
    float p1 = __builtin_amdgcn_exp2f(SF[1]);                    \
    float p2 = __builtin_amdgcn_exp2f(SF[2]);                    \
    float p3 = __builtin_amdgcn_exp2f(SF[3]);                    \
    lsum += (p0 + p1) + (p2 + p3);                               \
    pk[I2] = cvt_pk_bf16(p0, p1);                                \
    pk[I2 + 1] = cvt_pk_bf16(p2, p3); }

#define PVKT(KT, V0, V1, ACC0, ACC1) {                           \
    u32x2 bw; bw[0] = pk[2 * KT]; bw[1] = pk[2 * KT + 1];        \
    bf16x4 bb = as_bf16x4(bw);                                   \
    ACC0 = MFMA_PV(as_bf16x4(V0), bb, ACC0);                     \
    ACC1 = MFMA_PV(as_bf16x4(V1), bb, ACC1); }

// grid: 1024 blocks (32 b x 32 q-tiles of 64), 256 threads (4 waves x 16 q-rows)
__global__ __launch_bounds__(256, 4) void attn_kernel(
    const unsigned short* __restrict__ Qb, const unsigned short* __restrict__ KF,
    const unsigned short* __restrict__ VP, float* __restrict__ out) {
  __shared__ __align__(16) unsigned char lds[2][8192]; // 2 x (K 4KB | V 4KB)
  unsigned char* ldsb = &lds[0][0];
  int tid = threadIdx.x;
  int wv = tid >> 6, lane = tid & 63;
  int n = lane & 15, g = lane >> 4;

  // XCD-aware bijective swizzle (1024 % 8 == 0)
  int bid = blockIdx.x;
  int swz = (bid & 7) * 128 + (bid >> 3);
  int bi = swz >> 5, qt = swz & 31;

  size_t Rq = (size_t)bi * 2048 + qt * 64 + wv * 16;

  const unsigned char* Kg = (const unsigned char*)KF + (size_t)bi * 131072;
  const unsigned char* Vg = (const unsigned char*)VP + (size_t)bi * 131072;

  // staging: wave wv covers 2KB of the 8KB (K|V) tile; 2 x 16B per lane
  const unsigned char* sgp = (wv < 2 ? Kg : Vg) + (wv & 1) * 2048 + lane * 16;
  unsigned char* ldsw = ldsb + (wv < 2 ? 0 : 4096) + (wv & 1) * 2048 + lane * 16;

  bf16x8 qf = *(const bf16x8*)(Qb + (Rq + n) * 32 + g * 8);

  f32x4 oA0 = (f32x4)0.0f, oA1 = (f32x4)0.0f; // kt 0,1 x eblk 0,1
  f32x4 oB0 = (f32x4)0.0f, oB1 = (f32x4)0.0f; // kt 2,3 x eblk 0,1
  float lsum = 0.0f;

  bf16x8 kr0, kr1;

  // prologue: stage tile 0 into buf0
  kr0 = *(const bf16x8*)(sgp);
  kr1 = *(const bf16x8*)(sgp + 1024);
  sgp += 4096;
  *(bf16x8*)(ldsw) = kr0;
  *(bf16x8*)(ldsw + 1024) = kr1;
  __syncthreads();

  for (int t = 0; t < 32; ++t) {
    int buf = t & 1;
    if (t < 31) { // issue next tile's loads early (one compute phase of cover)
      kr0 = *(const bf16x8*)(sgp);
      kr1 = *(const bf16x8*)(sgp + 1024);
      sgp += 4096;
    }
    const unsigned char* Lp = ldsb + buf * 8192;
    bf16x8 kf0 = *(const bf16x8*)(Lp + lane * 16);
    bf16x8 kf1 = *(const bf16x8*)(Lp + lane * 16 + 1024);
    bf16x8 kf2 = *(const bf16x8*)(Lp + lane * 16 + 2048);
    bf16x8 kf3 = *(const bf16x8*)(Lp + lane * 16 + 3072);
    // V: 4 x b128, each = (kt=2p | kt=2p+1) pair for eblk e
    u32x4 w00 = *(const u32x4*)(Lp + 4096 + lane * 16);          // e0, kt0|kt1
    u32x4 w01 = *(const u32x4*)(Lp + 4096 + lane * 16 + 1024);   // e0, kt2|kt3
    u32x4 w10 = *(const u32x4*)(Lp + 4096 + lane * 16 + 2048);   // e1, kt0|kt1
    u32x4 w11 = *(const u32x4*)(Lp + 4096 + lane * 16 + 3072);   // e1, kt2|kt3
    u32x2 vf0; vf0[0] = w00[0]; vf0[1] = w00[1];
    u32x2 vf1; vf1[0] = w00[2]; vf1[1] = w00[3];
    u32x2 vf2; vf2[0] = w01[0]; vf2[1] = w01[1];
    u32x2 vf3; vf3[0] = w01[2]; vf3[1] = w01[3];
    u32x2 vf4; vf4[0] = w10[0]; vf4[1] = w10[1];
    u32x2 vf5; vf5[0] = w10[2]; vf5[1] = w10[3];
    u32x2 vf6; vf6[0] = w11[0]; vf6[1] = w11[1];
    u32x2 vf7; vf7[0] = w11[2]; vf7[1] = w11[3];
    f32x4 s0 = __builtin_amdgcn_mfma_f32_16x16x32_bf16(kf0, qf, (f32x4)0.0f, 0, 0, 0);
    f32x4 s1 = __builtin_amdgcn_mfma_f32_16x16x32_bf16(kf1, qf, (f32x4)0.0f, 0, 0, 0);
    f32x4 s2 = __builtin_amdgcn_mfma_f32_16x16x32_bf16(kf2, qf, (f32x4)0.0f, 0, 0, 0);
    f32x4 s3 = __builtin_amdgcn_mfma_f32_16x16x32_bf16(kf3, qf, (f32x4)0.0f, 0, 0, 0);
    unsigned pk[8];
    SMAX(s0, 0) SMAX(s1, 2) SMAX(s2, 4) SMAX(s3, 6)
    PVKT(0, vf0, vf4, oA0, oA1) PVKT(1, vf1, vf5, oA0, oA1)
    PVKT(2, vf2, vf6, oB0, oB1) PVKT(3, vf3, vf7, oB0, oB1)
    __syncthreads();              // all waves done reading buf
    if (t < 31) {
      unsigned char* Wp = ldsw + (buf ^ 1) * 8192;
      *(bf16x8*)(Wp) = kr0;       // compiler inserts vmcnt wait before ds_write
      *(bf16x8*)(Wp + 1024) = kr1;
      __syncthreads();            // stage of tile t+1 visible to all
    }
  }

  // full row-sum for q-row n: partials live in lanes n, n+16, n+32, n+48
  lsum += __shfl_xor(lsum, 16);
  lsum += __shfl_xor(lsum, 32);
  float inv = 1.0f / lsum;

  // O: lane(n,g) reg r holds O[q=Rq+n][e = eblk*16 + g*4 + r]
  f32x4 r0 = (oA0 + oB0) * inv;
  f32x4 r1 = (oA1 + oB1) * inv;
  float* ob = out + (Rq + n) * 32 + g * 4;
  *(f32x4*)(ob)      = r0;
  *(f32x4*)(ob + 16) = r1;
}

extern "C" void kernel_launch(void* const* d_in, const int* in_sizes, int n_in,
                              void* d_out, int out_size, void* d_ws, size_t ws_size,
                              hipStream_t stream) {
  const float* x = (const float*)d_in[0];
  const float* w = (const float*)d_in[1];
  float* out = (float*)d_out;

  unsigned short* KF = (unsigned short*)d_ws;          // 4MB, fragment-order K
  unsigned short* VP = KF + (size_t)65536 * 32;        // 4MB, paired fragment-order V
  unsigned short* Qb = VP + (size_t)65536 * 32;        // 4MB

  qkv_kernel<<<1024, 256, 0, stream>>>(x, w, Qb, KF, VP);
  attn_kernel<<<1024, 256, 0, stream>>>(Qb, KF, VP, out);
}